// Round 9
// baseline (109.953 us; speedup 1.0000x reference)
//
#include <hip/hip_runtime.h>
#include <hip/hip_bf16.h>
#include <math.h>

// MMD (InfoVAE RBF kernel), N=8192, D=128, fp32 in, scalar fp32 out.
//
// Round 19: A-fragments REGISTER-RESIDENT per segment; no LDS, no
// barriers, no hand waitcnts in the hot kernel; finish merged into mmd.
//   r18 post-mortem: 45.4us vs serial pipe sum ~50us -> overlap factor
//   only 1.25. A-frags are J-tile-INVARIANT: r18 re-read the same 16KB
//   LDS per tile (21x/segment) = ~10.3us LDS pipe + per-slice lgkm
//   stalls. Fix: hold ALL A-frags in VGPRs for the segment.
//   Geometry: tile 128(I)x64(J), 4 waves (2x2), wave-tile 64x32:
//   acc[4][2]=32 AGPR, a_all[4][4]=64 VGPR, b dbuf 2x4=32 VGPR, ar 16
//   -> ~158 unified regs <= 170 -> 3 waves/SIMD (launch_bounds(256,3)),
//   3 blocks/CU, grid 768 co-resident.
//   Schedule: r17 pair-balance at 64-col granularity: strip p paired
//   with 127-p: (256-2p)+(2+2p) = 258 tiles/pair, SPLIT=12 -> 21-22
//   tiles/block (was 10-11, spread halves). Two segments/block.
//   K pipelined in halves (2 planes = 64 K): bB (H1) issued before H0
//   MFMAs (310cy cover), next-tile bA (H0') before H1 MFMAs (~700cy).
//   All waits are compiler register-dependency waitcnts. setprio
//   dropped (m190: hurts free-running GEMM).
//   finish merged: per-block fp64 atomicAdd -> threadfence -> done-ctr;
//   last block re-reads 256 slots via atomicAdd(,0.0) (device-scope,
//   coherent) and writes out. Saves one kernel launch.
//   Numerics: per-element MFMA K-chain (planes 0..3 ascending, same
//   operand bytes via the r14-verified pre-swizzled plane layout:
//   addr = plane*1MB + row*64 + ((quad^((lr>>1)&3))<<4)) and epilogue
//   formula identical to r18 (passed 5.96e-8). fp32 partial regroup
//   16->8 terms (r13->r14's 32->16 left absmax bit-identical). fp64
//   accumulation order change ~1e-16. Weights: sign by X/Y boundary
//   (I<64 vs J64<128), x2 unless J64>>1==I (the old 128x128 diagonal).

#define NN 8192
#define DD 128
#define TZ 16384
#define SPLIT 12
#define NBLK (64 * SPLIT)                  // 768

typedef __attribute__((ext_vector_type(8))) short bf16x8;
typedef __attribute__((ext_vector_type(4))) float f32x4;
typedef __attribute__((ext_vector_type(2))) float f32x2;

#if __has_builtin(__builtin_amdgcn_exp2f)
#define EXP2F __builtin_amdgcn_exp2f
#else
#define EXP2F exp2f
#endif

constexpr float LOG2E = 0x1.715476p+0f;
constexpr float S2 = LOG2E / 8192.0f;              // 2*log2e/16384

constexpr size_t PLANE = 1048576;                  // 16384 rows x 64 B

// ---- ws layout ----
// sums: 256 fp64 @0; ctr: u32 @2048; normZ @2560; Zs @68096 (4 MB).
constexpr size_t WS_CTR  = 2048;
constexpr size_t WS_NORM = 2560;
constexpr size_t WS_Z    = WS_NORM + (size_t)TZ * sizeof(float);

__global__ __launch_bounds__(256) void prep(
    const float* __restrict__ X, const float* __restrict__ Y,
    char* __restrict__ Zs, float* __restrict__ normZ,
    double* __restrict__ sums, unsigned* __restrict__ ctr) {
  if (blockIdx.x == 0) {
    sums[threadIdx.x] = 0.0;                       // 256 slots
    if (threadIdx.x == 0) *ctr = 0u;
  }

  const int row = blockIdx.x * 4 + (threadIdx.x >> 6);
  const int lane = threadIdx.x & 63;
  const float* __restrict__ src =
      (row < NN) ? (X + (size_t)row * DD) : (Y + (size_t)(row - NN) * DD);
  const float2 v = *reinterpret_cast<const float2*>(src + 2 * lane);

  float n = v.x * v.x + v.y * v.y;

  // K-slice plane store, chunk pre-swizzled (r14-verified).
  const int ks = lane >> 4;
  const int quadc = (lane >> 2) & 3;
  const int inner = (lane & 3) * 4;
  char* dst = Zs + (size_t)ks * PLANE + (size_t)row * 64 +
              ((quadc ^ ((row >> 1) & 3)) << 4) + inner;
  *reinterpret_cast<__hip_bfloat162*>(dst) =
      __hip_bfloat162{__float2bfloat16(v.x), __float2bfloat16(v.y)};

#pragma unroll
  for (int o = 32; o > 0; o >>= 1) n += __shfl_down(n, o);
  if (lane == 0) normZ[row] = n * (-LOG2E / 16384.0f);  // pre-scaled
}

__global__ __launch_bounds__(256, 3) void mmd_mfma(
    const char* __restrict__ Zs, const float* __restrict__ normZ,
    double* __restrict__ sums, unsigned* __restrict__ ctr,
    float* __restrict__ out) {
  const int bid = blockIdx.x;
  const int p = bid / SPLIT, s = bid % SPLIT;
  const int q = 127 - p;
  // Pair list: strip p has 256-2p 64-col tiles, strip q has 2+2p; 258 total.
  const int n1 = (255 - 2 * p - s) / SPLIT + 1;
  const int u0 = s + SPLIT * n1 - (256 - 2 * p);   // in [0, SPLIT)
  const int n2 = (u0 <= 2 * p + 1) ? (2 * p + 1 - u0) / SPLIT + 1 : 0;

  const int segI[2]  = {p, q};
  const int segJ0[2] = {2 * p + s, 2 * q + u0};    // J in 64-col units
  const int segN[2]  = {n1, n2};

  const int tid = threadIdx.x;
  const int lane = tid & 63, wave = tid >> 6;      // 4 waves
  const int wr = wave >> 1, wc = wave & 1;         // 2x2: 64x32 per wave
  const int lr = lane & 15, quad = lane >> 4;

  // r13/r14-verified swizzle (identical on read & prep-store sides).
  const int csw = (quad ^ ((lr >> 1) & 3)) << 4;

  bf16x8 aAll[4][4];                               // [plane][i] - 64 VGPR
  bf16x8 bA[4], bB[4];                             // [half: pl*2+j]
  f32x4 ar[4];

  // dst[0]=(pl0,j0) dst[1]=(pl0,j1) dst[2]=(pl0+1,j0) dst[3]=(pl0+1,j1)
#define LOADBH(dst, base, pl0) do {                                         \
    dst[0] = *reinterpret_cast<const bf16x8*>((base) + (size_t)(pl0) * PLANE);        \
    dst[1] = *reinterpret_cast<const bf16x8*>((base) + (size_t)(pl0) * PLANE + 1024); \
    dst[2] = *reinterpret_cast<const bf16x8*>((base) + (size_t)(pl0 + 1) * PLANE);    \
    dst[3] = *reinterpret_cast<const bf16x8*>((base) + (size_t)(pl0 + 1) * PLANE + 1024); \
  } while (0)

  // Two K=32 slices (planes ks0, ks0+1) against one b-half buffer.
#define MFMAH(ks0, bb) do {                                                 \
    _Pragma("unroll")                                                       \
    for (int i = 0; i < 4; ++i)                                             \
      _Pragma("unroll")                                                     \
      for (int j = 0; j < 2; ++j)                                           \
        acc[i][j] = __builtin_amdgcn_mfma_f32_16x16x32_bf16(                \
            aAll[ks0][i], bb[j], acc[i][j], 0, 0, 0);                       \
    _Pragma("unroll")                                                       \
    for (int i = 0; i < 4; ++i)                                             \
      _Pragma("unroll")                                                     \
      for (int j = 0; j < 2; ++j)                                           \
        acc[i][j] = __builtin_amdgcn_mfma_f32_16x16x32_bf16(                \
            aAll[ks0 + 1][i], bb[2 + j], acc[i][j], 0, 0, 0);               \
  } while (0)

  const f32x2 s2v = {S2, S2};
  double blockAcc = 0.0;

  for (int seg = 0; seg < 2; ++seg) {
    const int I = segI[seg];
    const int nIter = segN[seg];
    if (nIter == 0) continue;                      // block-uniform
    int J = segJ0[seg];

    // I-side norms (f32x4 per frag-row-group).
    const float* nzA = normZ + I * 128 + wr * 64;
#pragma unroll
    for (int i = 0; i < 4; ++i)
      ar[i] = *reinterpret_cast<const f32x4*>(nzA + i * 16 + quad * 4);

    // A-fragments: register-resident for the whole segment (16 loads).
    const char* aBase = Zs + (size_t)(I * 128 + wr * 64 + lr) * 64 + csw;
#pragma unroll
    for (int ks = 0; ks < 4; ++ks)
#pragma unroll
      for (int i = 0; i < 4; ++i)
        aAll[ks][i] = *reinterpret_cast<const bf16x8*>(
            aBase + (size_t)ks * PLANE + i * 1024);

    // B base for first tile; prologue: bA <- H0 (planes 0,1).
    const char* bbase = Zs + (size_t)(J * 64 + wc * 32 + lr) * 64 + csw;
    LOADBH(bA, bbase, 0);

    for (int it = 0; it < nIter; ++it) {
      const char* bnext = (it + 1 < nIter) ? bbase + SPLIT * 4096 : bbase;
      f32x4 acc[4][2] = {};

      LOADBH(bB, bbase, 2);                        // H1 (planes 2,3)
      __builtin_amdgcn_sched_barrier(0);
      MFMAH(0, bA);                                // slices 0,1
      __builtin_amdgcn_sched_barrier(0);
      LOADBH(bA, bnext, 0);                        // next tile H0
      __builtin_amdgcn_sched_barrier(0);
      MFMAH(2, bB);                                // slices 2,3

      // ---- epilogue ----
      const float* nzB = normZ + J * 64 + wc * 32;
      const float cb0 = nzB[lr], cb1 = nzB[16 + lr];

      f32x2 part01 = {0.f, 0.f}, part23 = {0.f, 0.f};
#pragma unroll
      for (int i = 0; i < 4; ++i) {
        const f32x2 ar01 = {ar[i].x, ar[i].y};
        const f32x2 ar23 = {ar[i].z, ar[i].w};
#pragma unroll
        for (int j = 0; j < 2; ++j) {
          const float rb = j ? cb1 : cb0;
          const f32x2 rb2 = {rb, rb};
          const f32x2 base01 = ar01 + rb2;
          const f32x2 base23 = ar23 + rb2;
          const f32x2 acc01 = {acc[i][j][0], acc[i][j][1]};
          const f32x2 acc23 = {acc[i][j][2], acc[i][j][3]};
          const f32x2 arg01 = __builtin_elementwise_fma(acc01, s2v, base01);
          const f32x2 arg23 = __builtin_elementwise_fma(acc23, s2v, base23);
          part01 += (f32x2){EXP2F(arg01.x), EXP2F(arg01.y)};
          part23 += (f32x2){EXP2F(arg23.x), EXP2F(arg23.y)};
        }
      }
      const f32x2 ps = part01 + part23;
      double w = ((I < 64) == (J < 128)) ? 1.0 : -1.0;  // X/Y boundary
      if ((J >> 1) != I) w += w;                   // off the old diagonal
      blockAcc += (double)(ps.x + ps.y) * w;

      J += SPLIT;
      bbase = bnext;
    }
  }

#undef LOADBH
#undef MFMAH

  // ---- block reduce + merged finish ----
  __shared__ double red[4];
  __shared__ int lastFlag;
#pragma unroll
  for (int o = 32; o > 0; o >>= 1) blockAcc += __shfl_down(blockAcc, o);
  if (lane == 0) red[wave] = blockAcc;
  __syncthreads();
  if (tid == 0) {
    atomicAdd(&sums[bid & 255], red[0] + red[1] + red[2] + red[3]);
    __threadfence();
    lastFlag = (atomicAdd(ctr, 1u) == NBLK - 1);
  }
  __syncthreads();
  if (wave == 0 && lastFlag) {
    double v = 0.0;
#pragma unroll
    for (int k = 0; k < 4; ++k)
      v += atomicAdd(&sums[lane * 4 + k], 0.0);    // device-scope read
#pragma unroll
    for (int o = 32; o > 0; o >>= 1) v += __shfl_down(v, o);
    if (lane == 0)
      out[0] = (float)(v * (1.0 / ((double)NN * (double)NN)));
  }
}

extern "C" void kernel_launch(void* const* d_in, const int* in_sizes, int n_in,
                              void* d_out, int out_size, void* d_ws, size_t ws_size,
                              hipStream_t stream) {
  const float* y_inputs = (const float*)d_in[0];  // "inputs"
  const float* x_true   = (const float*)d_in[1];  // "true_samples"
  float* out = (float*)d_out;

  char* ws = (char*)d_ws;
  double* sums = (double*)ws;                     // 256 fp64 partial slots
  unsigned* ctr = (unsigned*)(ws + WS_CTR);
  float* normZ = (float*)(ws + WS_NORM);
  char* Zs = ws + WS_Z;

  prep<<<TZ / 4, 256, 0, stream>>>(x_true, y_inputs, Zs, normZ, sums, ctr);
  mmd_mfma<<<NBLK, 256, 0, stream>>>(Zs, normZ, sums, ctr, out);
}